// Round 8
// baseline (2002.591 us; speedup 1.0000x reference)
//
#include <hip/hip_runtime.h>
#include <hip/hip_bf16.h>

// Shapes (fixed by the reference): B=32, T=2048, D=512, H=128.
#define Bx 32
#define Tt 2048
#define Dd 512
#define Hh 128

typedef __attribute__((ext_vector_type(8))) short short8;   // 8 bf16 (4 VGPR)
typedef __attribute__((ext_vector_type(4))) float f32x4;    // MFMA C/D

static __device__ __forceinline__ short f2bf(float f) {
    __hip_bfloat16 h = __float2bfloat16(f);
    return *reinterpret_cast<short*>(&h);
}
static __device__ __forceinline__ float sigm(float x) {
    return 1.f / (1.f + __expf(-x));
}

// 16-lane-row DPP add stages (verified R5): xor1, xor2, ror4, ror8
template<int CTRL>
static __device__ __forceinline__ float dpp_add(float v) {
    return v + __int_as_float(__builtin_amdgcn_update_dpp(
        0, __float_as_int(v), CTRL, 0xF, 0xF, true));
}
static __device__ __forceinline__ float rowred16(float v) {
    v = dpp_add<0xB1>(v);
    v = dpp_add<0x4E>(v);
    v = dpp_add<0x124>(v);
    v = dpp_add<0x128>(v);
    return v;
}

// barrier that does NOT drain vmcnt
#define BARRIER_LGKM() asm volatile("s_waitcnt lgkmcnt(0)\n\ts_barrier" ::: "memory")

// async global->LDS, 16B per lane: LDS dest = uniform base + lane*16
typedef __attribute__((address_space(1))) const void gas_void;
typedef __attribute__((address_space(3))) void las_void;
static __device__ __forceinline__ void gl_lds16(const float* g, float* l) {
    __builtin_amdgcn_global_load_lds((gas_void*)g, (las_void*)l, 16, 0, 0);
}

// ---------------------------------------------------------------------------
// Phase 1: G = x @ [W_f|W_i|W_o|W_c], bf16 MFMA.  (verified R4-R7, ~90us)
// ---------------------------------------------------------------------------
__global__ __launch_bounds__(512, 2) void gemm_xw_mfma(
    const float* __restrict__ X,
    const float* __restrict__ W0, const float* __restrict__ W1,
    const float* __restrict__ W2, const float* __restrict__ W3,
    float* __restrict__ G)
{
    __shared__ __align__(16) short As[128][40];
    __shared__ __align__(16) short Bs[512][40];

    const int tid  = threadIdx.x;
    const int m0   = blockIdx.x * 128;
    const int lane = tid & 63;
    const int w    = tid >> 6;
    const int wr   = w >> 2, wc = w & 3;
    const int l15  = lane & 15, kb = lane >> 4;

    const int bn   = tid;
    const int gate = bn >> 7;
    const int j    = bn & 127;
    const float* __restrict__ Wg = (gate == 0) ? W0 : (gate == 1) ? W1 : (gate == 2) ? W2 : W3;

    const int am = tid >> 2;
    const int ak = (tid & 3) * 8;

    f32x4 acc[4][8];
    #pragma unroll
    for (int mt = 0; mt < 4; ++mt)
        #pragma unroll
        for (int nt = 0; nt < 8; ++nt)
            acc[mt][nt] = (f32x4){0.f, 0.f, 0.f, 0.f};

    for (int k0 = 0; k0 < Dd; k0 += 32) {
        {
            const float4* xp = (const float4*)&X[(size_t)(m0 + am) * Dd + k0 + ak];
            float4 v0 = xp[0], v1 = xp[1];
            short8 s;
            s[0] = f2bf(v0.x); s[1] = f2bf(v0.y); s[2] = f2bf(v0.z); s[3] = f2bf(v0.w);
            s[4] = f2bf(v1.x); s[5] = f2bf(v1.y); s[6] = f2bf(v1.z); s[7] = f2bf(v1.w);
            *(short8*)&As[am][ak] = s;
        }
        #pragma unroll
        for (int rc = 0; rc < 4; ++rc) {
            float v[8];
            #pragma unroll
            for (int r = 0; r < 8; ++r)
                v[r] = Wg[(size_t)(k0 + rc * 8 + r) * Hh + j];
            short8 s;
            #pragma unroll
            for (int r = 0; r < 8; ++r) s[r] = f2bf(v[r]);
            *(short8*)&Bs[bn][rc * 8] = s;
        }
        __syncthreads();

        short8 a[4], b[8];
        #pragma unroll
        for (int mt = 0; mt < 4; ++mt)
            a[mt] = *(const short8*)&As[wr * 64 + mt * 16 + l15][kb * 8];
        #pragma unroll
        for (int nt = 0; nt < 8; ++nt)
            b[nt] = *(const short8*)&Bs[wc * 128 + nt * 16 + l15][kb * 8];
        #pragma unroll
        for (int mt = 0; mt < 4; ++mt)
            #pragma unroll
            for (int nt = 0; nt < 8; ++nt)
                acc[mt][nt] = __builtin_amdgcn_mfma_f32_16x16x32_bf16(a[mt], b[nt], acc[mt][nt], 0, 0, 0);
        __syncthreads();
    }

    #pragma unroll
    for (int mt = 0; mt < 4; ++mt)
        #pragma unroll
        for (int nt = 0; nt < 8; ++nt)
            #pragma unroll
            for (int r = 0; r < 4; ++r)
                G[(size_t)(m0 + wr * 64 + mt * 16 + kb * 4 + r) * 512 + wc * 128 + nt * 16 + l15]
                    = acc[mt][nt][r];
}

// ---------------------------------------------------------------------------
// Phase 2: MFMA scan, 2-phase / 2-barrier step.
// Phase A: MFMA -> s=C+G+bias in lanes 0..15 -> in-register DPP stats ->
//          write s-frags (ST) + stat pairs (SQr).  [barrier]
// Phase B: thread (ob,oj) = owner: read 4 gate pre-acts + stats, finish LN
//          locally, sigmoid, c/h update, Ap write, out store.  [barrier]
// ---------------------------------------------------------------------------
__global__ __launch_bounds__(512, 1) void lstm_scan_mfma(
    const float* __restrict__ G,
    const float* __restrict__ Uf, const float* __restrict__ Ui,
    const float* __restrict__ Uo, const float* __restrict__ Uc,
    const float* __restrict__ bf_, const float* __restrict__ bi_,
    const float* __restrict__ bo_, const float* __restrict__ bc_,
    const float* __restrict__ lnfg, const float* __restrict__ lnfb,
    const float* __restrict__ lnig, const float* __restrict__ lnib,
    const float* __restrict__ lnog, const float* __restrict__ lnob,
    const float* __restrict__ lncg, const float* __restrict__ lncb,
    const float* __restrict__ h0, const float* __restrict__ c0,
    const int* __restrict__ zmask,
    float* __restrict__ out, float* __restrict__ hT)
{
    const int tid  = threadIdx.x;
    const int lane = tid & 63;
    const int w    = tid >> 6;          // wave 0..7
    const int b0   = blockIdx.x * 4;    // 4 batches per block

    __shared__ __align__(16) short Ap[16 * 136];     // h panel bf16 [row=b][k]
    __shared__ __align__(16) float ST[512 * 10];     // s transposed [col][b]
    __shared__ __align__(16) float2 SQr[4][8];       // [b][w] = (sum, sumsq) partials
    __shared__ __align__(16) float Pan[2 * 4 * 4 * 512]; // [buf][slot][b][col] 64KB
    __shared__ unsigned short act[Tt];
    __shared__ int wsum[8], wpre[8];
    __shared__ int nact_sh;

    // ---- B fragments: U columns in bf16 (wave w -> gate w>>1, 64 cols) ----
    const int gate = w >> 1;
    const float* __restrict__ Ug = (gate == 0) ? Uf : (gate == 1) ? Ui : (gate == 2) ? Uo : Uc;
    const int n0  = w * 64;
    const int l15 = lane & 15;
    const int kb  = lane >> 4;

    short8 bfr[4][4];
    #pragma unroll
    for (int nt = 0; nt < 4; ++nt) {
        const int jloc = (n0 & 127) + nt * 16 + l15;
        #pragma unroll
        for (int ks = 0; ks < 4; ++ks) {
            short8 v;
            #pragma unroll
            for (int r = 0; r < 8; ++r)
                v[r] = f2bf(Ug[(ks * 32 + kb * 8 + r) * Hh + jloc]);
            bfr[nt][ks] = v;
        }
    }

    // ---- Phase-A per-thread bias at cols n0+nt*16+l15 (gate `gate`) ----
    const float* __restrict__ bgA = (gate == 0) ? bf_ : (gate == 1) ? bi_ : (gate == 2) ? bo_ : bc_;
    float biasA[4];
    #pragma unroll
    for (int nt = 0; nt < 4; ++nt)
        biasA[nt] = bgA[(n0 & 127) + nt * 16 + l15];

    // ---- Phase-B (owner) constants: thread = (ob = tid>>7, oj = tid&127) ----
    const int ob = tid >> 7;
    const int oj = tid & 127;
    const float gamF = lnfg[oj], betF = lnfb[oj];
    const float gamI = lnig[oj], betI = lnib[oj];
    const float gamO = lnog[oj], betO = lnob[oj];
    const float gamC = lncg[oj], betC = lncb[oj];

    float hval = h0[(b0 + ob) * Hh + oj];
    float cval = c0[(b0 + ob) * Hh + oj];

    for (int i = tid; i < 16 * 136; i += 512) Ap[i] = 0;
    __syncthreads();
    Ap[ob * 136 + oj] = f2bf(hval);

    // ---- parallel active-list build ----
    {
        const int base_t = tid * 4;
        const int f0 = (zmask[base_t] == 0), f1 = (zmask[base_t + 1] == 0);
        const int f2 = (zmask[base_t + 2] == 0), f3 = (zmask[base_t + 3] == 0);
        const int cnt = f0 + f1 + f2 + f3;
        int scan = cnt;
        #pragma unroll
        for (int off = 1; off <= 32; off <<= 1) {
            int v = __shfl_up(scan, off);
            if (lane >= off) scan += v;
        }
        if (lane == 63) wsum[w] = scan;
        __syncthreads();
        if (tid == 0) {
            int s = 0;
            #pragma unroll
            for (int i = 0; i < 8; ++i) { wpre[i] = s; s += wsum[i]; }
            nact_sh = s;
        }
        __syncthreads();
        int pos = wpre[w] + scan - cnt;
        if (f0) act[pos++] = (unsigned short)(base_t);
        if (f1) act[pos++] = (unsigned short)(base_t + 1);
        if (f2) act[pos++] = (unsigned short)(base_t + 2);
        if (f3) act[pos++] = (unsigned short)(base_t + 3);
    }
    __syncthreads();
    const int nact = nact_sh;

    // ---- G panel staging (verified R7): wave w loads slices {2w, 2w+1} ----
    auto stage_panel = [&](int kp, int buf) {
        #pragma unroll
        for (int si = 0; si < 2; ++si) {
            const int s    = w * 2 + si;
            const int slot = s >> 2;
            const int bb   = s & 3;
            const int kidx = kp + slot;
            if (kidx < nact) {
                const int tt = (int)act[kidx];
                const float* src = &G[((size_t)(b0 + bb) * Tt + tt) * 512];
                float* dst = &Pan[((buf * 4 + slot) * 4 + bb) * 512];
                gl_lds16(src + lane * 4, dst);
                gl_lds16(src + 256 + lane * 4, dst + 256);
            }
        }
    };

    int cur = 0;
    stage_panel(0, 0);
    asm volatile("s_waitcnt vmcnt(0)" ::: "memory");
    __syncthreads();

    auto lstm_step = [&](int kidx, int slot) {
        const int t_ = (int)act[kidx];

        // ================= Phase A =================
        // G panel reads (needed only after MFMA; latency hides under it)
        float Gv[4][4];
        #pragma unroll
        for (int nt = 0; nt < 4; ++nt)
            #pragma unroll
            for (int r = 0; r < 4; ++r)
                Gv[nt][r] = Pan[((cur * 4 + slot) * 4 + r) * 512 + n0 + nt * 16 + l15];

        short8 a0 = *(const short8*)&Ap[l15 * 136 +  0 + kb * 8];
        short8 a1 = *(const short8*)&Ap[l15 * 136 + 32 + kb * 8];
        short8 a2 = *(const short8*)&Ap[l15 * 136 + 64 + kb * 8];
        short8 a3 = *(const short8*)&Ap[l15 * 136 + 96 + kb * 8];

        f32x4 C0 = {0.f, 0.f, 0.f, 0.f}, C1 = C0, C2 = C0, C3 = C0;
        C0 = __builtin_amdgcn_mfma_f32_16x16x32_bf16(a0, bfr[0][0], C0, 0, 0, 0);
        C1 = __builtin_amdgcn_mfma_f32_16x16x32_bf16(a0, bfr[1][0], C1, 0, 0, 0);
        C2 = __builtin_amdgcn_mfma_f32_16x16x32_bf16(a0, bfr[2][0], C2, 0, 0, 0);
        C3 = __builtin_amdgcn_mfma_f32_16x16x32_bf16(a0, bfr[3][0], C3, 0, 0, 0);
        C0 = __builtin_amdgcn_mfma_f32_16x16x32_bf16(a1, bfr[0][1], C0, 0, 0, 0);
        C1 = __builtin_amdgcn_mfma_f32_16x16x32_bf16(a1, bfr[1][1], C1, 0, 0, 0);
        C2 = __builtin_amdgcn_mfma_f32_16x16x32_bf16(a1, bfr[2][1], C2, 0, 0, 0);
        C3 = __builtin_amdgcn_mfma_f32_16x16x32_bf16(a1, bfr[3][1], C3, 0, 0, 0);
        C0 = __builtin_amdgcn_mfma_f32_16x16x32_bf16(a2, bfr[0][2], C0, 0, 0, 0);
        C1 = __builtin_amdgcn_mfma_f32_16x16x32_bf16(a2, bfr[1][2], C1, 0, 0, 0);
        C2 = __builtin_amdgcn_mfma_f32_16x16x32_bf16(a2, bfr[2][2], C2, 0, 0, 0);
        C3 = __builtin_amdgcn_mfma_f32_16x16x32_bf16(a2, bfr[3][2], C3, 0, 0, 0);
        C0 = __builtin_amdgcn_mfma_f32_16x16x32_bf16(a3, bfr[0][3], C0, 0, 0, 0);
        C1 = __builtin_amdgcn_mfma_f32_16x16x32_bf16(a3, bfr[1][3], C1, 0, 0, 0);
        C2 = __builtin_amdgcn_mfma_f32_16x16x32_bf16(a3, bfr[2][3], C2, 0, 0, 0);
        C3 = __builtin_amdgcn_mfma_f32_16x16x32_bf16(a3, bfr[3][3], C3, 0, 0, 0);

        // s = C + G + bias (rows 4..15 are zero-A garbage: finite, ignored)
        f32x4 s0, s1, s2, s3;
        #pragma unroll
        for (int r = 0; r < 4; ++r) {
            s0[r] = C0[r] + Gv[0][r] + biasA[0];
            s1[r] = C1[r] + Gv[1][r] + biasA[1];
            s2[r] = C2[r] + Gv[2][r] + biasA[2];
            s3[r] = C3[r] + Gv[3][r] + biasA[3];
        }

        // in-register stats over the wave's 64 cols (lanes 0..15 hold real rows)
        float ps0 = s0[0] + s1[0] + s2[0] + s3[0];
        float ps1 = s0[1] + s1[1] + s2[1] + s3[1];
        float ps2 = s0[2] + s1[2] + s2[2] + s3[2];
        float ps3 = s0[3] + s1[3] + s2[3] + s3[3];
        float pq0 = s0[0]*s0[0] + s1[0]*s1[0] + s2[0]*s2[0] + s3[0]*s3[0];
        float pq1 = s0[1]*s0[1] + s1[1]*s1[1] + s2[1]*s2[1] + s3[1]*s3[1];
        float pq2 = s0[2]*s0[2] + s1[2]*s1[2] + s2[2]*s2[2] + s3[2]*s3[2];
        float pq3 = s0[3]*s0[3] + s1[3]*s1[3] + s2[3]*s2[3] + s3[3]*s3[3];
        ps0 = rowred16(ps0); ps1 = rowred16(ps1); ps2 = rowred16(ps2); ps3 = rowred16(ps3);
        pq0 = rowred16(pq0); pq1 = rowred16(pq1); pq2 = rowred16(pq2); pq3 = rowred16(pq3);

        // write s fragments (lanes 0..15) + stat pairs (lane 0)
        if (lane < 16) {
            #pragma unroll
            for (int nt = 0; nt < 4; ++nt) {
                const int col = n0 + nt * 16 + l15;
                const f32x4& sv = (nt == 0) ? s0 : (nt == 1) ? s1 : (nt == 2) ? s2 : s3;
                *(float2*)&ST[col * 10]     = make_float2(sv[0], sv[1]);
                *(float2*)&ST[col * 10 + 2] = make_float2(sv[2], sv[3]);
            }
        }
        if (lane == 0) {
            SQr[0][w] = make_float2(ps0, pq0);
            SQr[1][w] = make_float2(ps1, pq1);
            SQr[2][w] = make_float2(ps2, pq2);
            SQr[3][w] = make_float2(ps3, pq3);
        }
        BARRIER_LGKM();

        // ================= Phase B (owner = (ob, oj)) =================
        const float sF = ST[(0   + oj) * 10 + ob];
        const float sI = ST[(128 + oj) * 10 + ob];
        const float sO = ST[(256 + oj) * 10 + ob];
        const float sC = ST[(384 + oj) * 10 + ob];
        // stats: SQr[ob][2g] + SQr[ob][2g+1]
        f32x4 q01 = *(const f32x4*)&SQr[ob][0];   // {sF0,qF0,sF1,qF1}
        f32x4 q23 = *(const f32x4*)&SQr[ob][2];   // gate I halves
        f32x4 q45 = *(const f32x4*)&SQr[ob][4];   // gate O halves
        f32x4 q67 = *(const f32x4*)&SQr[ob][6];   // gate C halves
        const float SF = q01[0] + q01[2], QF = q01[1] + q01[3];
        const float SI = q23[0] + q23[2], QI = q23[1] + q23[3];
        const float SO = q45[0] + q45[2], QO = q45[1] + q45[3];
        const float SC = q67[0] + q67[2], QC = q67[1] + q67[3];
        const float muF = SF * (1.f/128.f), rF = rsqrtf(QF*(1.f/128.f) - muF*muF + 1e-5f);
        const float muI = SI * (1.f/128.f), rI = rsqrtf(QI*(1.f/128.f) - muI*muI + 1e-5f);
        const float muO = SO * (1.f/128.f), rO = rsqrtf(QO*(1.f/128.f) - muO*muO + 1e-5f);
        const float muC = SC * (1.f/128.f), rC = rsqrtf(QC*(1.f/128.f) - muC*muC + 1e-5f);
        const float gf  = sigm((sF - muF) * rF * gamF + betF);
        const float gi  = sigm((sI - muI) * rI * gamI + betI);
        const float go  = sigm((sO - muO) * rO * gamO + betO);
        const float gch = sigm((sC - muC) * rC * gamC + betC);
        cval = gf * cval + gi * gch;
        hval = go * sigm(cval);                      // NB: sigmoid, not tanh
        Ap[ob * 136 + oj] = f2bf(hval);
        out[((size_t)(b0 + ob) * Tt + t_) * Hh + oj] = hval;
    };

    for (int kp = 0; kp < nact; kp += 4) {
        stage_panel(kp + 4, cur ^ 1);                // issue next panel early
        const int lim = (nact - kp < 4) ? (nact - kp) : 4;
        #pragma unroll
        for (int sl = 0; sl < 4; ++sl) {
            if (sl < lim) {
                lstm_step(kp + sl, sl);
                if (sl == 3)                          // once per group: drain DMA
                    asm volatile("s_waitcnt vmcnt(0)" ::: "memory");
                BARRIER_LGKM();
            }
        }
        cur ^= 1;
    }

    hT[(b0 + ob) * Hh + oj] = hval;
}

// ---------------------------------------------------------------------------
// Phase 3: fill zoneout timesteps (verified R7).
// ---------------------------------------------------------------------------
__global__ __launch_bounds__(512) void fill_zoneout(
    const int* __restrict__ zmask, const float* __restrict__ h0,
    float* __restrict__ out)
{
    const int t = blockIdx.x;
    if (zmask[t] == 0) return;            // active: scan wrote it
    int s = t - 1;
    while (s >= 0 && zmask[s] != 0) --s;
    const int tid = threadIdx.x;
    for (int idx = tid; idx < Bx * Hh; idx += 512) {
        const int b = idx >> 7, j = idx & 127;
        const float v = (s >= 0) ? out[((size_t)b * Tt + s) * Hh + j]
                                 : h0[b * Hh + j];
        out[((size_t)b * Tt + t) * Hh + j] = v;
    }
}

// ---------------------------------------------------------------------------
extern "C" void kernel_launch(void* const* d_in, const int* in_sizes, int n_in,
                              void* d_out, int out_size, void* d_ws, size_t ws_size,
                              hipStream_t stream)
{
    const float* x   = (const float*)d_in[0];
    const float* W_f = (const float*)d_in[1];
    const float* W_i = (const float*)d_in[2];
    const float* W_o = (const float*)d_in[3];
    const float* W_c = (const float*)d_in[4];
    const float* U_f = (const float*)d_in[5];
    const float* U_i = (const float*)d_in[6];
    const float* U_o = (const float*)d_in[7];
    const float* U_c = (const float*)d_in[8];
    const float* b_f = (const float*)d_in[9];
    const float* b_i = (const float*)d_in[10];
    const float* b_o = (const float*)d_in[11];
    const float* b_c = (const float*)d_in[12];
    const float* ln_f_g = (const float*)d_in[13];
    const float* ln_f_b = (const float*)d_in[14];
    const float* ln_i_g = (const float*)d_in[15];
    const float* ln_i_b = (const float*)d_in[16];
    const float* ln_o_g = (const float*)d_in[17];
    const float* ln_o_b = (const float*)d_in[18];
    const float* ln_c_g = (const float*)d_in[19];
    const float* ln_c_b = (const float*)d_in[20];
    const float* h0  = (const float*)d_in[21];
    const float* c0  = (const float*)d_in[22];
    const int*   zm  = (const int*)d_in[23];

    float* out = (float*)d_out;                       // [B, T, H]
    float* hT  = out + (size_t)Bx * Tt * Hh;          // [B, H]
    float* G   = (float*)d_ws;                        // [B*T, 512] = 128 MiB

    gemm_xw_mfma<<<(Bx * Tt) / 128, 512, 0, stream>>>(x, W_f, W_i, W_o, W_c, G);

    lstm_scan_mfma<<<8, 512, 0, stream>>>(G, U_f, U_i, U_o, U_c,
                                          b_f, b_i, b_o, b_c,
                                          ln_f_g, ln_f_b, ln_i_g, ln_i_b,
                                          ln_o_g, ln_o_b, ln_c_g, ln_c_b,
                                          h0, c0, zm, out, hT);

    fill_zoneout<<<Tt, 512, 0, stream>>>(zm, h0, out);
}

// Round 9
// 1737.876 us; speedup vs baseline: 1.1523x; 1.1523x over previous
//
#include <hip/hip_runtime.h>
#include <hip/hip_bf16.h>

// Shapes (fixed by the reference): B=32, T=2048, D=512, H=128.
#define Bx 32
#define Tt 2048
#define Dd 512
#define Hh 128
#define PROW 520   // padded panel/ST row (floats): 520%32=8 -> 2-way max on b128

typedef __attribute__((ext_vector_type(8))) short short8;   // 8 bf16 (4 VGPR)
typedef __attribute__((ext_vector_type(4))) float f32x4;    // MFMA C/D

static __device__ __forceinline__ short f2bf(float f) {
    __hip_bfloat16 h = __float2bfloat16(f);
    return *reinterpret_cast<short*>(&h);
}
static __device__ __forceinline__ float sigm(float x) {
    return 1.f / (1.f + __expf(-x));
}
static __device__ __forceinline__ float swz_xor16(float v) {
    return __int_as_float(__builtin_amdgcn_ds_swizzle(__float_as_int(v), 0x401F));
}

// barrier that does NOT drain vmcnt
#define BARRIER_LGKM() asm volatile("s_waitcnt lgkmcnt(0)\n\ts_barrier" ::: "memory")

// async global->LDS, 16B per lane: LDS dest = uniform base + lane*16
typedef __attribute__((address_space(1))) const void gas_void;
typedef __attribute__((address_space(3))) void las_void;
static __device__ __forceinline__ void gl_lds16(const float* g, float* l) {
    __builtin_amdgcn_global_load_lds((gas_void*)g, (las_void*)l, 16, 0, 0);
}

// ---------------------------------------------------------------------------
// Phase 1: G = x @ [W_f|W_i|W_o|W_c] + bias, bf16 MFMA. Bias folded into
// accumulator init (added exactly once). (structure verified R4-R8, ~90us)
// ---------------------------------------------------------------------------
__global__ __launch_bounds__(512, 2) void gemm_xw_mfma(
    const float* __restrict__ X,
    const float* __restrict__ W0, const float* __restrict__ W1,
    const float* __restrict__ W2, const float* __restrict__ W3,
    const float* __restrict__ B0, const float* __restrict__ B1,
    const float* __restrict__ B2, const float* __restrict__ B3,
    float* __restrict__ G)
{
    __shared__ __align__(16) short As[128][40];
    __shared__ __align__(16) short Bs[512][40];

    const int tid  = threadIdx.x;
    const int m0   = blockIdx.x * 128;
    const int lane = tid & 63;
    const int w    = tid >> 6;
    const int wr   = w >> 2, wc = w & 3;
    const int l15  = lane & 15, kb = lane >> 4;

    const int bn   = tid;
    const int gate = bn >> 7;
    const int j    = bn & 127;
    const float* __restrict__ Wg = (gate == 0) ? W0 : (gate == 1) ? W1 : (gate == 2) ? W2 : W3;

    const int am = tid >> 2;
    const int ak = (tid & 3) * 8;

    // wave's columns are wc*128.. -> gate wc; bias per nt-tile column
    const float* __restrict__ Bg = (wc == 0) ? B0 : (wc == 1) ? B1 : (wc == 2) ? B2 : B3;
    f32x4 acc[4][8];
    #pragma unroll
    for (int nt = 0; nt < 8; ++nt) {
        const float bv = Bg[nt * 16 + l15];
        #pragma unroll
        for (int mt = 0; mt < 4; ++mt)
            acc[mt][nt] = (f32x4){bv, bv, bv, bv};
    }

    for (int k0 = 0; k0 < Dd; k0 += 32) {
        {
            const float4* xp = (const float4*)&X[(size_t)(m0 + am) * Dd + k0 + ak];
            float4 v0 = xp[0], v1 = xp[1];
            short8 s;
            s[0] = f2bf(v0.x); s[1] = f2bf(v0.y); s[2] = f2bf(v0.z); s[3] = f2bf(v0.w);
            s[4] = f2bf(v1.x); s[5] = f2bf(v1.y); s[6] = f2bf(v1.z); s[7] = f2bf(v1.w);
            *(short8*)&As[am][ak] = s;
        }
        #pragma unroll
        for (int rc = 0; rc < 4; ++rc) {
            float v[8];
            #pragma unroll
            for (int r = 0; r < 8; ++r)
                v[r] = Wg[(size_t)(k0 + rc * 8 + r) * Hh + j];
            short8 s;
            #pragma unroll
            for (int r = 0; r < 8; ++r) s[r] = f2bf(v[r]);
            *(short8*)&Bs[bn][rc * 8] = s;
        }
        __syncthreads();

        short8 a[4], b[8];
        #pragma unroll
        for (int mt = 0; mt < 4; ++mt)
            a[mt] = *(const short8*)&As[wr * 64 + mt * 16 + l15][kb * 8];
        #pragma unroll
        for (int nt = 0; nt < 8; ++nt)
            b[nt] = *(const short8*)&Bs[wc * 128 + nt * 16 + l15][kb * 8];
        #pragma unroll
        for (int mt = 0; mt < 4; ++mt)
            #pragma unroll
            for (int nt = 0; nt < 8; ++nt)
                acc[mt][nt] = __builtin_amdgcn_mfma_f32_16x16x32_bf16(a[mt], b[nt], acc[mt][nt], 0, 0, 0);
        __syncthreads();
    }

    #pragma unroll
    for (int mt = 0; mt < 4; ++mt)
        #pragma unroll
        for (int nt = 0; nt < 8; ++nt)
            #pragma unroll
            for (int r = 0; r < 4; ++r)
                G[(size_t)(m0 + wr * 64 + mt * 16 + kb * 4 + r) * 512 + wc * 128 + nt * 16 + l15]
                    = acc[mt][nt][r];
}

// ---------------------------------------------------------------------------
// Phase 2: MFMA scan, operand-swapped: D[j][batch] = mfma(A=U^T, B=h^T).
// A/B fragment lane maps are identical for 16x16x32 (both confirmed R3-R8),
// so bfr/h reads are unchanged -- only the argument order swaps.
// C layout (m89): col=lane&15 -> batch, row=kb*4+reg -> j-local. Hence:
//  - C init = ds_read_b128 from per-batch G panel rows (no adds)
//  - lane-local LN partial sums (16 values, one (batch,gate) each)
//  - one ds_swizzle xor16 fold; 2x2 partials folded in phase B
// ---------------------------------------------------------------------------
__global__ __launch_bounds__(512, 1) void lstm_scan_mfma(
    const float* __restrict__ G,
    const float* __restrict__ Uf, const float* __restrict__ Ui,
    const float* __restrict__ Uo, const float* __restrict__ Uc,
    const float* __restrict__ lnfg, const float* __restrict__ lnfb,
    const float* __restrict__ lnig, const float* __restrict__ lnib,
    const float* __restrict__ lnog, const float* __restrict__ lnob,
    const float* __restrict__ lncg, const float* __restrict__ lncb,
    const float* __restrict__ h0, const float* __restrict__ c0,
    const int* __restrict__ zmask,
    float* __restrict__ out, float* __restrict__ hT)
{
    const int tid  = threadIdx.x;
    const int lane = tid & 63;
    const int w    = tid >> 6;          // wave 0..7
    const int b0   = blockIdx.x * 4;    // 4 batches per block

    __shared__ __align__(16) short Ap[16 * 136];        // h panel bf16 [row=b][k]
    __shared__ __align__(16) float STb[4 * PROW];       // s [b][col]
    __shared__ __align__(16) float2 SQf[4][4][2][2];    // [g][b][half][pair]
    __shared__ __align__(16) float Pan[2 * 4 * 4 * PROW]; // [buf][slot][b][col]
    __shared__ unsigned short act[Tt];
    __shared__ int wsum[8], wpre[8];
    __shared__ int nact_sh;

    // ---- A fragments: U columns in bf16 (wave w -> gate w>>1, 64 cols) ----
    const int gate = w >> 1;
    const float* __restrict__ Ug = (gate == 0) ? Uf : (gate == 1) ? Ui : (gate == 2) ? Uo : Uc;
    const int n0  = w * 64;
    const int l15 = lane & 15;
    const int kb  = lane >> 4;

    short8 bfr[4][4];
    #pragma unroll
    for (int nt = 0; nt < 4; ++nt) {
        const int jloc = (n0 & 127) + nt * 16 + l15;
        #pragma unroll
        for (int ks = 0; ks < 4; ++ks) {
            short8 v;
            #pragma unroll
            for (int r = 0; r < 8; ++r)
                v[r] = f2bf(Ug[(ks * 32 + kb * 8 + r) * Hh + jloc]);
            bfr[nt][ks] = v;
        }
    }

    // ---- Phase-B (owner) constants: thread = (ob = tid>>7, oj = tid&127) ----
    const int ob = tid >> 7;
    const int oj = tid & 127;
    const float gamF = lnfg[oj], betF = lnfb[oj];
    const float gamI = lnig[oj], betI = lnib[oj];
    const float gamO = lnog[oj], betO = lnob[oj];
    const float gamC = lncg[oj], betC = lncb[oj];

    float hval = h0[(b0 + ob) * Hh + oj];
    float cval = c0[(b0 + ob) * Hh + oj];

    for (int i = tid; i < 16 * 136; i += 512) Ap[i] = 0;
    __syncthreads();
    Ap[ob * 136 + oj] = f2bf(hval);

    // ---- parallel active-list build ----
    {
        const int base_t = tid * 4;
        const int f0 = (zmask[base_t] == 0), f1 = (zmask[base_t + 1] == 0);
        const int f2 = (zmask[base_t + 2] == 0), f3 = (zmask[base_t + 3] == 0);
        const int cnt = f0 + f1 + f2 + f3;
        int scan = cnt;
        #pragma unroll
        for (int off = 1; off <= 32; off <<= 1) {
            int v = __shfl_up(scan, off);
            if (lane >= off) scan += v;
        }
        if (lane == 63) wsum[w] = scan;
        __syncthreads();
        if (tid == 0) {
            int s = 0;
            #pragma unroll
            for (int i = 0; i < 8; ++i) { wpre[i] = s; s += wsum[i]; }
            nact_sh = s;
        }
        __syncthreads();
        int pos = wpre[w] + scan - cnt;
        if (f0) act[pos++] = (unsigned short)(base_t);
        if (f1) act[pos++] = (unsigned short)(base_t + 1);
        if (f2) act[pos++] = (unsigned short)(base_t + 2);
        if (f3) act[pos++] = (unsigned short)(base_t + 3);
    }
    __syncthreads();
    const int nact = nact_sh;

    // ---- G panel staging: wave w loads slices {2w, 2w+1} (padded rows) ----
    auto stage_panel = [&](int kp, int buf) {
        #pragma unroll
        for (int si = 0; si < 2; ++si) {
            const int s    = w * 2 + si;
            const int slot = s >> 2;
            const int bb   = s & 3;
            const int kidx = kp + slot;
            if (kidx < nact) {
                const int tt = (int)act[kidx];
                const float* src = &G[((size_t)(b0 + bb) * Tt + tt) * 512];
                float* dst = &Pan[((buf * 4 + slot) * 4 + bb) * PROW];
                gl_lds16(src + lane * 4, dst);
                gl_lds16(src + 256 + lane * 4, dst + 256);
            }
        }
    };

    int cur = 0;
    stage_panel(0, 0);
    asm volatile("s_waitcnt vmcnt(0)" ::: "memory");
    __syncthreads();

    const int lb = l15 & 3;   // batch for C-frag reads (l15>=4 dup, ignored)

    auto lstm_step = [&](int kidx, int slot) {
        const int t_ = (int)act[kidx];

        // ================= Phase A =================
        // h fragments (B operand): B[k][col=batch=l15]
        short8 a0 = *(const short8*)&Ap[l15 * 136 +  0 + kb * 8];
        short8 a1 = *(const short8*)&Ap[l15 * 136 + 32 + kb * 8];
        short8 a2 = *(const short8*)&Ap[l15 * 136 + 64 + kb * 8];
        short8 a3 = *(const short8*)&Ap[l15 * 136 + 96 + kb * 8];

        // C init = G panel b128 (batch lb, cols n0+nt*16+kb*4 .. +3)
        const int pbase = ((cur * 4 + slot) * 4 + lb) * PROW + n0 + kb * 4;
        f32x4 C0 = *(const f32x4*)&Pan[pbase];
        f32x4 C1 = *(const f32x4*)&Pan[pbase + 16];
        f32x4 C2 = *(const f32x4*)&Pan[pbase + 32];
        f32x4 C3 = *(const f32x4*)&Pan[pbase + 48];

        // D[j][b] += U^T . h^T : swapped operands, 4 independent nt chains
        C0 = __builtin_amdgcn_mfma_f32_16x16x32_bf16(bfr[0][0], a0, C0, 0, 0, 0);
        C1 = __builtin_amdgcn_mfma_f32_16x16x32_bf16(bfr[1][0], a0, C1, 0, 0, 0);
        C2 = __builtin_amdgcn_mfma_f32_16x16x32_bf16(bfr[2][0], a0, C2, 0, 0, 0);
        C3 = __builtin_amdgcn_mfma_f32_16x16x32_bf16(bfr[3][0], a0, C3, 0, 0, 0);
        C0 = __builtin_amdgcn_mfma_f32_16x16x32_bf16(bfr[0][1], a1, C0, 0, 0, 0);
        C1 = __builtin_amdgcn_mfma_f32_16x16x32_bf16(bfr[1][1], a1, C1, 0, 0, 0);
        C2 = __builtin_amdgcn_mfma_f32_16x16x32_bf16(bfr[2][1], a1, C2, 0, 0, 0);
        C3 = __builtin_amdgcn_mfma_f32_16x16x32_bf16(bfr[3][1], a1, C3, 0, 0, 0);
        C0 = __builtin_amdgcn_mfma_f32_16x16x32_bf16(bfr[0][2], a2, C0, 0, 0, 0);
        C1 = __builtin_amdgcn_mfma_f32_16x16x32_bf16(bfr[1][2], a2, C1, 0, 0, 0);
        C2 = __builtin_amdgcn_mfma_f32_16x16x32_bf16(bfr[2][2], a2, C2, 0, 0, 0);
        C3 = __builtin_amdgcn_mfma_f32_16x16x32_bf16(bfr[3][2], a2, C3, 0, 0, 0);
        C0 = __builtin_amdgcn_mfma_f32_16x16x32_bf16(bfr[0][3], a3, C0, 0, 0, 0);
        C1 = __builtin_amdgcn_mfma_f32_16x16x32_bf16(bfr[1][3], a3, C1, 0, 0, 0);
        C2 = __builtin_amdgcn_mfma_f32_16x16x32_bf16(bfr[2][3], a3, C2, 0, 0, 0);
        C3 = __builtin_amdgcn_mfma_f32_16x16x32_bf16(bfr[3][3], a3, C3, 0, 0, 0);

        // lane-local LN partials: 16 s-values, all (batch=l15, gate)
        float ps = ((C0[0] + C0[1]) + (C0[2] + C0[3]))
                 + ((C1[0] + C1[1]) + (C1[2] + C1[3]))
                 + ((C2[0] + C2[1]) + (C2[2] + C2[3]))
                 + ((C3[0] + C3[1]) + (C3[2] + C3[3]));
        float pq = C0[0]*C0[0] + C0[1]*C0[1] + C0[2]*C0[2] + C0[3]*C0[3]
                 + C1[0]*C1[0] + C1[1]*C1[1] + C1[2]*C1[2] + C1[3]*C1[3]
                 + C2[0]*C2[0] + C2[1]*C2[1] + C2[2]*C2[2] + C2[3]*C2[3]
                 + C3[0]*C3[0] + C3[1]*C3[1] + C3[2]*C3[2] + C3[3]*C3[3];
        // fold kb pairs (0,1) and (2,3): lane^16
        ps += swz_xor16(ps);
        pq += swz_xor16(pq);

        // s fragments -> STb[b][col] (b128, lanes l15<4)
        if (l15 < 4) {
            const int sbase = l15 * PROW + n0 + kb * 4;
            *(f32x4*)&STb[sbase]      = C0;
            *(f32x4*)&STb[sbase + 16] = C1;
            *(f32x4*)&STb[sbase + 32] = C2;
            *(f32x4*)&STb[sbase + 48] = C3;
            if ((kb & 1) == 0)
                SQf[gate][l15][w & 1][kb >> 1] = make_float2(ps, pq);
        }
        BARRIER_LGKM();

        // ================= Phase B (owner = (ob, oj)) =================
        const float sF = STb[ob * PROW +   0 + oj];
        const float sI = STb[ob * PROW + 128 + oj];
        const float sO = STb[ob * PROW + 256 + oj];
        const float sC = STb[ob * PROW + 384 + oj];
        f32x4 qF0 = *(const f32x4*)&SQf[0][ob][0][0];
        f32x4 qF1 = *(const f32x4*)&SQf[0][ob][1][0];
        f32x4 qI0 = *(const f32x4*)&SQf[1][ob][0][0];
        f32x4 qI1 = *(const f32x4*)&SQf[1][ob][1][0];
        f32x4 qO0 = *(const f32x4*)&SQf[2][ob][0][0];
        f32x4 qO1 = *(const f32x4*)&SQf[2][ob][1][0];
        f32x4 qC0 = *(const f32x4*)&SQf[3][ob][0][0];
        f32x4 qC1 = *(const f32x4*)&SQf[3][ob][1][0];
        const float SF = (qF0[0] + qF0[2]) + (qF1[0] + qF1[2]);
        const float QF = (qF0[1] + qF0[3]) + (qF1[1] + qF1[3]);
        const float SI = (qI0[0] + qI0[2]) + (qI1[0] + qI1[2]);
        const float QI = (qI0[1] + qI0[3]) + (qI1[1] + qI1[3]);
        const float SO = (qO0[0] + qO0[2]) + (qO1[0] + qO1[2]);
        const float QO = (qO0[1] + qO0[3]) + (qO1[1] + qO1[3]);
        const float SC = (qC0[0] + qC0[2]) + (qC1[0] + qC1[2]);
        const float QC = (qC0[1] + qC0[3]) + (qC1[1] + qC1[3]);
        const float muF = SF * (1.f/128.f), rF = rsqrtf(QF*(1.f/128.f) - muF*muF + 1e-5f);
        const float muI = SI * (1.f/128.f), rI = rsqrtf(QI*(1.f/128.f) - muI*muI + 1e-5f);
        const float muO = SO * (1.f/128.f), rO = rsqrtf(QO*(1.f/128.f) - muO*muO + 1e-5f);
        const float muC = SC * (1.f/128.f), rC = rsqrtf(QC*(1.f/128.f) - muC*muC + 1e-5f);
        const float gf  = sigm((sF - muF) * rF * gamF + betF);
        const float gi  = sigm((sI - muI) * rI * gamI + betI);
        const float go  = sigm((sO - muO) * rO * gamO + betO);
        const float gch = sigm((sC - muC) * rC * gamC + betC);
        cval = gf * cval + gi * gch;
        hval = go * sigm(cval);                      // NB: sigmoid, not tanh
        Ap[ob * 136 + oj] = f2bf(hval);
        out[((size_t)(b0 + ob) * Tt + t_) * Hh + oj] = hval;
    };

    for (int kp = 0; kp < nact; kp += 4) {
        stage_panel(kp + 4, cur ^ 1);                // issue next panel early
        const int lim = (nact - kp < 4) ? (nact - kp) : 4;
        #pragma unroll
        for (int sl = 0; sl < 4; ++sl) {
            if (sl < lim) {
                lstm_step(kp + sl, sl);
                if (sl == 3)                          // once per group: drain DMA
                    asm volatile("s_waitcnt vmcnt(0)" ::: "memory");
                BARRIER_LGKM();
            }
        }
        cur ^= 1;
    }

    hT[(b0 + ob) * Hh + oj] = hval;
}

// ---------------------------------------------------------------------------
// Phase 3: fill zoneout timesteps (verified R7/R8).
// ---------------------------------------------------------------------------
__global__ __launch_bounds__(512) void fill_zoneout(
    const int* __restrict__ zmask, const float* __restrict__ h0,
    float* __restrict__ out)
{
    const int t = blockIdx.x;
    if (zmask[t] == 0) return;            // active: scan wrote it
    int s = t - 1;
    while (s >= 0 && zmask[s] != 0) --s;
    const int tid = threadIdx.x;
    for (int idx = tid; idx < Bx * Hh; idx += 512) {
        const int b = idx >> 7, j = idx & 127;
        const float v = (s >= 0) ? out[((size_t)b * Tt + s) * Hh + j]
                                 : h0[b * Hh + j];
        out[((size_t)b * Tt + t) * Hh + j] = v;
    }
}

// ---------------------------------------------------------------------------
extern "C" void kernel_launch(void* const* d_in, const int* in_sizes, int n_in,
                              void* d_out, int out_size, void* d_ws, size_t ws_size,
                              hipStream_t stream)
{
    const float* x   = (const float*)d_in[0];
    const float* W_f = (const float*)d_in[1];
    const float* W_i = (const float*)d_in[2];
    const float* W_o = (const float*)d_in[3];
    const float* W_c = (const float*)d_in[4];
    const float* U_f = (const float*)d_in[5];
    const float* U_i = (const float*)d_in[6];
    const float* U_o = (const float*)d_in[7];
    const float* U_c = (const float*)d_in[8];
    const float* b_f = (const float*)d_in[9];
    const float* b_i = (const float*)d_in[10];
    const float* b_o = (const float*)d_in[11];
    const float* b_c = (const float*)d_in[12];
    const float* ln_f_g = (const float*)d_in[13];
    const float* ln_f_b = (const float*)d_in[14];
    const float* ln_i_g = (const float*)d_in[15];
    const float* ln_i_b = (const float*)d_in[16];
    const float* ln_o_g = (const float*)d_in[17];
    const float* ln_o_b = (const float*)d_in[18];
    const float* ln_c_g = (const float*)d_in[19];
    const float* ln_c_b = (const float*)d_in[20];
    const float* h0  = (const float*)d_in[21];
    const float* c0  = (const float*)d_in[22];
    const int*   zm  = (const int*)d_in[23];

    float* out = (float*)d_out;                       // [B, T, H]
    float* hT  = out + (size_t)Bx * Tt * Hh;          // [B, H]
    float* G   = (float*)d_ws;                        // [B*T, 512] = 128 MiB

    gemm_xw_mfma<<<(Bx * Tt) / 128, 512, 0, stream>>>(x, W_f, W_i, W_o, W_c,
                                                      b_f, b_i, b_o, b_c, G);

    lstm_scan_mfma<<<8, 512, 0, stream>>>(G, U_f, U_i, U_o, U_c,
                                          ln_f_g, ln_f_b, ln_i_g, ln_i_b,
                                          ln_o_g, ln_o_b, ln_c_g, ln_c_b,
                                          h0, c0, zm, out, hT);

    fill_zoneout<<<Tt, 512, 0, stream>>>(zm, h0, out);
}